// Round 4
// baseline (2293.529 us; speedup 1.0000x reference)
//
#include <hip/hip_runtime.h>
#include <cstdint>
#include <cmath>

// ConvLSTM2D x2, B=8 T=10 H=W=64 Cin=32 F=64, split-bf16 MFMA implicit GEMM.
// Round 9: R8 (cross-layer fused, (256,3), 1648us) + XCD-aware role-
// interleaved block mapping. Rocprof R8: fused 171us vs 86us MFMA floor,
// MfmaUtil 45%, FETCH 98MB vs ~53 ideal -> halo rows re-fetched per XCD and
// L1-heavy dispatch front. Mapping: block i<1024 -> xcd=i&7, slot=i>>3,
// work w = xcd*64 + slot/2, role = slot&1. Batch k pinned to XCD k (row
// halos, h/c state, relu source all stay in that XCD's L2 across steps);
// L1/L2 alternate in dispatch order. Standalone steps use the same remap;
// the final L2-step-9 launch also absorbs relu(out[8]) (grid 768).

#define NT        256   // step-kernel threads (4 waves)
#define NTU       256   // utility-kernel threads
#define RELU_BLKS 256   // relu tail blocks inside fused launch

typedef __attribute__((ext_vector_type(8))) short short8;
typedef __attribute__((ext_vector_type(4))) float f32x4;

__device__ __forceinline__ float hsig(float v) {
    return fminf(fmaxf(fmaf(v, 0.2f, 0.5f), 0.0f), 1.0f);
}

__device__ __forceinline__ short bf16rnd(float f) {
    union { float f; unsigned u; } a; a.f = f;
    return (short)((a.u + 0x7FFFu + ((a.u >> 16) & 1u)) >> 16);
}

__device__ __forceinline__ void split_bf16(float f, short& h, short& l) {
    h = bf16rnd(f);
    union { unsigned u; float f; } b; b.u = ((unsigned)(unsigned short)h) << 16;
    l = bf16rnd(f - b.f);
}

__device__ __forceinline__ float from_bf16(short s) {
    union { unsigned u; float f; } b; b.u = ((unsigned)(unsigned short)s) << 16;
    return b.f;
}

struct BF { uint4 bh[4]; uint4 bl[4]; };   // 4 gates x (hi,lo) fragments

// Batch-local relu tail: 32 blocks per batch, 262144 elems per batch.
__device__ __forceinline__ void relu_tail(
    int bat, int j, const short* __restrict__ relu_src,
    float* __restrict__ relu_dst, long out_bstride)
{
    const long pbase = (long)bat * 4096;
    for (long le = (long)j * NT + threadIdx.x; le < 262144; le += 32L * NT) {
        long pr  = le >> 6;                  // batch-local pixel
        int  c   = (int)(le & 63);
        long pix = pbase + pr;
        float f = from_bf16(relu_src[pix * 128 + c])
                + from_bf16(relu_src[pix * 128 + 64 + c]);
        relu_dst[(long)bat * out_bstride + pr * 64 + c] = fmaxf(f, 0.0f);
    }
}

// One ConvLSTM step body. bidx = batch*64 + y (batch 0..7, row 0..63);
// 256 threads, wave w handles gate filter-group fg = w. HZ: h_prev/c_state
// known zero -> skip h staging, h segs, c read (exact: zero contributes 0).
template<int CINX, int KS, bool WRITE_SEQ, bool HZ>
__device__ __forceinline__ void step_body(
    short* __restrict__ xs, short* __restrict__ hs,
    const short* __restrict__ xp, long xp_bstride,     // shorts
    const short* __restrict__ h_prev,
    float* __restrict__ c_state,
    const short* __restrict__ Wpk,
    const short* __restrict__ Upk,
    const float* __restrict__ bias,
    short* __restrict__ h_next,
    short* __restrict__ seq, long seq_bstride,         // shorts
    int bidx)
{
    constexpr int PAD  = KS / 2;
    constexpr int COLS = 64 + 2 * PAD;
    constexpr int CHX  = CINX / 32;
    constexpr int SEGS = HZ ? CHX : (CHX + 2);  // x chunks (+ 2 h chunks)
    constexpr int PSTX = 2 * CINX + 8;          // shorts per px (x buf)
    constexpr int PSTH = 136;                   // shorts per px (h buf)
    constexpr int VPPX = CINX / 4;              // uint4 per px (x)

    const int tid  = threadIdx.x;
    const int lane = tid & 63;
    const int fg   = tid >> 6;                 // 0..3 gate filter-group
    const int q8   = ((lane >> 4) & 3) * 8;
    const int batch = bidx >> 6;
    const int y     = bidx & 63;

    const short* xim = xp + (size_t)batch * xp_bstride;
    const short* him = h_prev + (size_t)batch * 4096 * 128;

    // zero LDS buffers (halo stays zero; interior overwritten per ky)
    for (int idx = tid; idx < (COLS * PSTX) / 8; idx += NT) {
        uint4 z; z.x = 0; z.y = 0; z.z = 0; z.w = 0;
        *(uint4*)(xs + idx * 8) = z;
    }
    if constexpr (!HZ) {
        for (int idx = tid; idx < (COLS * PSTH) / 8; idx += NT) {
            uint4 z; z.x = 0; z.y = 0; z.z = 0; z.w = 0;
            *(uint4*)(hs + idx * 8) = z;
        }
    }

    f32x4 acc[4][4];
    #pragma unroll
    for (int g = 0; g < 4; ++g)
        #pragma unroll
        for (int mt = 0; mt < 4; ++mt)
            #pragma unroll
            for (int r = 0; r < 4; ++r) acc[g][mt][r] = 0.0f;

    // B-fragment loader: seg s<CHX -> Wpk chunk s; else Upk chunk s-CHX.
    auto loadB = [&](int ky, int kx, int s) -> BF {
        int tap = ky * KS + kx;
        const short* base;
        if (s < CHX)
            base = Wpk + ((size_t)((tap * CHX + s) * 16 + fg)) * 1024 + lane * 16;
        else
            base = Upk + ((size_t)((tap * 2 + (s - CHX)) * 16 + fg)) * 1024 + lane * 16;
        BF b;
        #pragma unroll
        for (int g = 0; g < 4; ++g) {
            b.bh[g] = *(const uint4*)(base + (size_t)g * 4096);
            b.bl[g] = *(const uint4*)(base + (size_t)g * 4096 + 8);
        }
        return b;
    };

    const int ky0   = (y < PAD) ? (PAD - y) : 0;
    const int kyend = (64 + PAD - y) < KS ? (64 + PAD - y) : KS;

    BF bcur = loadB(ky0, 0, 0);

    for (int ky = ky0; ky < kyend; ++ky) {
        int yin = y + ky - PAD;                     // always in [0,64)
        __syncthreads();                            // prior readers done
        const short* xrow = xim + (size_t)yin * 64 * 2 * CINX;
        for (int idx = tid; idx < 64 * VPPX; idx += NT) {
            int px = idx / VPPX;                    // pow2
            int v  = idx - px * VPPX;
            *(uint4*)(xs + (px + PAD) * PSTX + v * 8)
                = *(const uint4*)(xrow + px * 2 * CINX + v * 8);
        }
        if constexpr (!HZ) {
            const short* hrow = him + (size_t)yin * 64 * 128;
            for (int idx = tid; idx < 64 * 16; idx += NT) {
                int px = idx >> 4;
                int v  = idx & 15;
                *(uint4*)(hs + (px + PAD) * PSTH + v * 8)
                    = *(const uint4*)(hrow + px * 128 + v * 8);
            }
        }
        __syncthreads();

        #pragma unroll
        for (int kx = 0; kx < KS; ++kx) {
            #pragma unroll
            for (int s = 0; s < SEGS; ++s) {
                // next (s,kx,ky) in iteration order; ky clamped (extra load
                // of a valid address on the final step, harmless)
                int ns = s + 1, nkx = kx, nky = ky;
                if (ns == SEGS) { ns = 0; ++nkx; }
                if (nkx == KS)  { nkx = 0; ++nky; }
                nky = (nky < kyend) ? nky : ky;
                BF bnxt = loadB(nky, nkx, ns);      // prefetch (global)

                short8 ah[4], al[4];
                #pragma unroll
                for (int mt = 0; mt < 4; ++mt) {
                    int col = mt * 16 + (lane & 15) + kx;
                    const short* p = (s < CHX)
                        ? (xs + col * PSTX + s * 32 + q8)
                        : (hs + col * PSTH + (s - CHX) * 32 + q8);
                    int lo = (s < CHX) ? CINX : 64;
                    ah[mt] = *(const short8*)p;
                    al[mt] = *(const short8*)(p + lo);
                }
                #pragma unroll
                for (int g = 0; g < 4; ++g) {
                    short8 bh = *(const short8*)&bcur.bh[g];
                    short8 bl = *(const short8*)&bcur.bl[g];
                    #pragma unroll
                    for (int mt = 0; mt < 4; ++mt) {
                        acc[g][mt] = __builtin_amdgcn_mfma_f32_16x16x32_bf16(
                            ah[mt], bh, acc[g][mt], 0, 0, 0);
                        acc[g][mt] = __builtin_amdgcn_mfma_f32_16x16x32_bf16(
                            al[mt], bh, acc[g][mt], 0, 0, 0);
                        acc[g][mt] = __builtin_amdgcn_mfma_f32_16x16x32_bf16(
                            ah[mt], bl, acc[g][mt], 0, 0, 0);
                    }
                }
                bcur = bnxt;
            }
        }
    }

    // ---- epilogue (layout verified R2/R3) ----
    const int fl = fg * 16 + (lane & 15);
    const float b_i = bias[fl];
    const float b_f = bias[64 + fl];
    const float b_c = bias[128 + fl];
    const float b_o = bias[192 + fl];
    const int q = (lane >> 4) & 3;

    const long pixbase = (long)batch * 4096 + (long)y * 64;
    const long cb = pixbase * 64 + fl;
    const long sb = (long)batch * seq_bstride + ((long)y * 64) * 128 + fl;

    #pragma unroll
    for (int mt = 0; mt < 4; ++mt) {
        #pragma unroll
        for (int r = 0; r < 4; ++r) {
            int col = mt * 16 + q * 4 + r;
            long cidx = cb + (long)col * 64;
            float zi = acc[0][mt][r] + b_i;
            float zf = acc[1][mt][r] + b_f;
            float zc = acc[2][mt][r] + b_c;
            float zo = acc[3][mt][r] + b_o;
            float ig = hsig(zi);
            float fgt = hsig(zf);
            float og = hsig(zo);
            float cp = HZ ? 0.0f : c_state[cidx];
            float cn = fgt * cp + ig * tanhf(zc);
            float hn = og * tanhf(cn);
            c_state[cidx] = cn;

            short hh, hl;
            split_bf16(hn, hh, hl);
            long hoff = (pixbase + col) * 128 + fl;
            h_next[hoff]      = hh;
            h_next[hoff + 64] = hl;
            if (WRITE_SEQ) {
                bool pos = hn > 0.0f;
                seq[sb + (long)col * 128]      = pos ? hh : (short)0;
                seq[sb + (long)col * 128 + 64] = pos ? hl : (short)0;
            }
        }
    }
}

// Standalone step kernel. Blocks 0..511: step with batch-per-XCD remap
// (bidx = (i&7)*64 + i/8). Blocks 512..767 (if launched): relu tail.
template<int CINX, int KS, bool WRITE_SEQ, bool HZ>
__global__ __launch_bounds__(NT, 2)
void convlstm_step(
    const short* __restrict__ xp, long xp_bstride,
    const short* __restrict__ h_prev,
    float* __restrict__ c_state,
    const short* __restrict__ Wpk,
    const short* __restrict__ Upk,
    const float* __restrict__ bias,
    short* __restrict__ h_next,
    short* __restrict__ seq, long seq_bstride,
    const short* __restrict__ relu_src, float* __restrict__ relu_dst,
    long out_bstride)
{
    extern __shared__ __align__(16) short smem[];
    const int i = (int)blockIdx.x;
    if (i >= 512) {
        if (relu_dst == nullptr) return;
        const int ri = i - 512;
        relu_tail(ri & 7, ri >> 3, relu_src, relu_dst, out_bstride);
        return;
    }
    constexpr int PAD  = KS / 2;
    constexpr int COLS = 64 + 2 * PAD;
    constexpr int PSTX = 2 * CINX + 8;
    const int bidx = ((i & 7) << 6) | (i >> 3);   // batch = i&7 -> XCD i&7
    step_body<CINX, KS, WRITE_SEQ, HZ>(
        smem, smem + COLS * PSTX,
        xp, xp_bstride, h_prev, c_state, Wpk, Upk, bias,
        h_next, seq, seq_bstride, bidx);
}

// Fused launch. i<1024: xcd=i&7, slot=i>>3, work w=xcd*64+slot/2,
// role = slot&1 (0 -> L1 step t, 1 -> L2 step t-1; L2 reads seq[t-1]
// written by the PREVIOUS launch). Batch k pinned to XCD k; L1/L2
// alternate in dispatch order. i>=1024: relu(out[t-2]) from h2p (nobody
// writes h2p this launch), batch-partitioned (bat = i&7).
__global__ __launch_bounds__(NT, 3)
void convlstm_fused(
    const short* __restrict__ x1, long x1_bs,
    const short* __restrict__ h1p, float* __restrict__ c1,
    const short* __restrict__ Wp1, const short* __restrict__ Up1,
    const float* __restrict__ b1,
    short* __restrict__ h1n, short* __restrict__ seq1, long seq1_bs,
    const short* __restrict__ x2, long x2_bs,
    const short* __restrict__ h2p, float* __restrict__ c2,
    const short* __restrict__ Wp2, const short* __restrict__ Up2,
    const float* __restrict__ b2,
    short* __restrict__ h2n,
    const short* __restrict__ relu_src, float* __restrict__ relu_dst,
    long out_bstride)
{
    extern __shared__ __align__(16) short smem[];
    const int i = (int)blockIdx.x;
    if (i < 1024) {
        const int xcd  = i & 7;
        const int slot = i >> 3;
        const int w    = (xcd << 6) | (slot >> 1);
        if ((slot & 1) == 0) {
            step_body<32, 5, true, false>(
                smem, smem + 68 * 72,
                x1, x1_bs, h1p, c1, Wp1, Up1, b1, h1n, seq1, seq1_bs, w);
        } else {
            step_body<64, 3, false, false>(
                smem, smem + 66 * 136,
                x2, x2_bs, h2p, c2, Wp2, Up2, b2, h2n, nullptr, 0, w);
        }
    } else {
        if (relu_dst == nullptr) return;
        const int ri = i - 1024;
        relu_tail(ri & 7, ri >> 3, relu_src, relu_dst, out_bstride);
    }
}

// fp32 x [Npix][32] -> hi/lo planes [Npix]{32 hi,32 lo}. One thread = 4 ch.
__global__ void convert_planes32(const float4* __restrict__ src,
                                 unsigned* __restrict__ dst, int n4)
{
    int t = blockIdx.x * NTU + threadIdx.x;
    if (t >= n4) return;
    int pix = t >> 3;
    int c4  = t & 7;
    float4 v = src[t];
    short h0, l0, h1, l1, h2, l2, h3, l3;
    split_bf16(v.x, h0, l0);
    split_bf16(v.y, h1, l1);
    split_bf16(v.z, h2, l2);
    split_bf16(v.w, h3, l3);
    unsigned* p = dst + (size_t)pix * 32;
    p[c4 * 2]      = (unsigned)(unsigned short)h0 | ((unsigned)(unsigned short)h1 << 16);
    p[c4 * 2 + 1]  = (unsigned)(unsigned short)h2 | ((unsigned)(unsigned short)h3 << 16);
    p[16 + c4 * 2]     = (unsigned)(unsigned short)l0 | ((unsigned)(unsigned short)l1 << 16);
    p[16 + c4 * 2 + 1] = (unsigned)(unsigned short)l2 | ((unsigned)(unsigned short)l3 << 16);
}

// Repack fp32 weights [KS,KS,CIN,256] -> B-fragment hi/lo layout (verified R2).
__global__ void repack(const float* __restrict__ src, short* __restrict__ dst,
                       int KS, int CH)
{
    int total = KS * KS * CH * 16 * 64;
    int t = blockIdx.x * NTU + threadIdx.x;
    if (t >= total) return;
    int u = t >> 6, lane = t & 63;
    int tap = u / (CH * 16);
    int rem = u - tap * (CH * 16);
    int ch = rem >> 4;
    int gfg = rem & 15;
    int g = gfg >> 2, fgp = gfg & 3;
    int CIN = CH * 32;
    int n = lane & 15, qq = lane >> 4;
    short* d = dst + (size_t)u * 1024 + lane * 16;
    int gc = g * 64 + fgp * 16 + n;
    for (int j = 0; j < 8; ++j) {
        int c = ch * 32 + qq * 8 + j;
        float w = src[((size_t)tap * CIN + c) * 256 + gc];
        short h, l;
        split_bf16(w, h, l);
        d[j] = h;
        d[8 + j] = l;
    }
}

// out[b, t, pix, c] = relu(hi/lo planes h)
__global__ void relu_copy(const short* __restrict__ hp, float* __restrict__ out,
                          long out_bstride)
{
    long i = (long)blockIdx.x * NTU + threadIdx.x;   // 0 .. 2^21-1
    long pix = i >> 6;
    int c = (int)(i & 63);
    float f = from_bf16(hp[pix * 128 + c]) + from_bf16(hp[pix * 128 + 64 + c]);
    long b = pix >> 12;
    long within = (pix & 4095) * 64 + c;
    out[b * out_bstride + within] = fmaxf(f, 0.0f);
}

extern "C" void kernel_launch(void* const* d_in, const int* in_sizes, int n_in,
                              void* d_out, int out_size, void* d_ws, size_t ws_size,
                              hipStream_t stream) {
    const float* x   = (const float*)d_in[0];   // [8,10,64,64,32]
    const float* Wk1 = (const float*)d_in[1];   // [5,5,32,256]
    const float* Uk1 = (const float*)d_in[2];   // [5,5,64,256]
    const float* b1  = (const float*)d_in[3];   // [256]
    const float* Wk2 = (const float*)d_in[4];   // [3,3,64,256]
    const float* Uk2 = (const float*)d_in[5];   // [3,3,64,256]
    const float* b2  = (const float*)d_in[6];   // [256]
    float* out = (float*)d_out;                 // [8,10,64,64,64]

    const long S  = (long)8 * 64 * 64 * 64;     // 2,097,152 state elems
    const long oT = (long)64 * 64 * 64;         // out t-stride (floats)
    const long oB = 10 * oT;                    // out batch-stride (floats)
    const long x1T = (long)4096 * 64;           // x-plane t-stride (shorts)
    const long x1B = 10 * x1T;                  // x-plane batch-stride (shorts)

    // sizes (bytes)
    const size_t HB  = (size_t)4 * S;                 // one h plane buffer
    const size_t CB  = (size_t)4 * S;                 // one c buffer
    const size_t W1B = (size_t)25 * 1 * 16 * 1024 * 2;
    const size_t U1B = (size_t)25 * 2 * 16 * 1024 * 2;
    const size_t W2B = (size_t)9 * 2 * 16 * 1024 * 2;
    const size_t U2B = (size_t)9 * 2 * 16 * 1024 * 2;
    const size_t XPB = (size_t)8 * x1B * 2;           // FULL 8-batch x planes
    const size_t need_ov = 4 * HB + 2 * CB + W1B + U1B + W2B + U2B + XPB;
    const bool ov = (ws_size >= need_ov);

    short* h1a = (short*)d_ws;
    short* h1b = h1a + 2 * S;
    short *h2a, *h2b;
    float *c1, *c2;
    short* Wp1;
    if (ov) {
        h2a = h1b + 2 * S;
        h2b = h2a + 2 * S;
        c1  = (float*)(h2b + 2 * S);
        c2  = c1 + S;
        Wp1 = (short*)(c2 + S);
    } else {
        h2a = h1a; h2b = h1b;               // serial reuse
        c1  = (float*)(h1b + 2 * S);
        c2  = c1;
        Wp1 = (short*)(c1 + S);
    }
    short* Up1 = Wp1 + 25 * 1 * 16 * 1024;
    short* Wp2 = Up1 + 25 * 2 * 16 * 1024;
    short* Up2 = Wp2 + 9 * 2 * 16 * 1024;
    short* x1p = Up2 + 9 * 2 * 16 * 1024;   // x planes: 8*10*4096*64 shorts

    {
        int n4 = 8 * 10 * 4096 * 8;
        convert_planes32<<<dim3((n4 + NTU - 1) / NTU), dim3(NTU), 0, stream>>>(
            (const float4*)x, (unsigned*)x1p, n4);
    }
    repack<<<dim3((25 * 1 * 16 * 64 + NTU - 1) / NTU), dim3(NTU), 0, stream>>>(Wk1, Wp1, 5, 1);
    repack<<<dim3((25 * 2 * 16 * 64 + NTU - 1) / NTU), dim3(NTU), 0, stream>>>(Uk1, Up1, 5, 2);
    repack<<<dim3((9 * 2 * 16 * 64 + NTU - 1) / NTU), dim3(NTU), 0, stream>>>(Wk2, Wp2, 3, 2);
    repack<<<dim3((9 * 2 * 16 * 64 + NTU - 1) / NTU), dim3(NTU), 0, stream>>>(Uk2, Up2, 3, 2);

    short* seqs = (short*)d_out;            // seq planes live in d_out slots

    // dynamic LDS sizes (bytes)
    const size_t SH_L1HZ = (size_t)(68 * 72) * 2;                 //  9,792
    const size_t SH_L1   = (size_t)(68 * 72 + 68 * 136) * 2;      // 28,288
    const size_t SH_L2   = (size_t)(66 * 136) * 4;                // 35,904
    const size_t SH_F    = SH_L2;

    if (ov) {
        // zero L2 initial state (h2a, c2); L1 step 0 handles its own zeros
        // via the HZ body (writes c1/h1b fully, so no memset needed for L1).
        hipMemsetAsync(h2a, 0, HB, stream);
        hipMemsetAsync(c2, 0, CB, stream);

        // L1 step 0 (h==0): x-conv only, writes h1b + seq[0]
        convlstm_step<32, 5, true, true><<<dim3(512), dim3(NT), SH_L1HZ, stream>>>(
            x1p, x1B, h1a, c1, Wp1, Up1, b1, h1b, seqs, oB * 2,
            nullptr, nullptr, 0);

        short* hc1 = h1b; short* hn1 = h1a;
        short* hc2 = h2a; short* hn2 = h2b;
        for (int t = 1; t < 10; ++t) {
            const short* x2 = seqs + (size_t)(t - 1) * oT * 2;
            float* rdst = (t >= 2) ? (out + (size_t)(t - 2) * oT) : (float*)nullptr;
            convlstm_fused<<<dim3(1024 + RELU_BLKS), dim3(NT), SH_F, stream>>>(
                x1p + (size_t)t * x1T, x1B, hc1, c1, Wp1, Up1, b1, hn1,
                seqs + (size_t)t * oT * 2, oB * 2,
                x2, oB * 2, hc2, c2, Wp2, Up2, b2, hn2,
                hc2, rdst, oB);
            short* tmp;
            tmp = hc1; hc1 = hn1; hn1 = tmp;
            tmp = hc2; hc2 = hn2; hn2 = tmp;
        }
        // L2 step 9 (+relu(out[8]) tail reading hc2, untouched this launch),
        // then the final relu for out[9].
        convlstm_step<64, 3, false, false><<<dim3(512 + RELU_BLKS), dim3(NT), SH_L2, stream>>>(
            seqs + (size_t)9 * oT * 2, oB * 2, hc2, c2, Wp2, Up2, b2, hn2,
            nullptr, 0, hc2, out + 8 * oT, oB);
        relu_copy<<<dim3(8192), dim3(NTU), 0, stream>>>(hn2, out + 9 * oT, oB);
    } else {
        // ---- serial fallback (R5-verified footprint; HZ for L1 step 0) ----
        convlstm_step<32, 5, true, true><<<dim3(512), dim3(NT), SH_L1HZ, stream>>>(
            x1p, x1B, h1a, c1, Wp1, Up1, b1, h1b, seqs, oB * 2,
            nullptr, nullptr, 0);
        short* hc = h1b; short* hn = h1a;
        for (int t = 1; t < 10; ++t) {
            convlstm_step<32, 5, true, false><<<dim3(512), dim3(NT), SH_L1, stream>>>(
                x1p + (size_t)t * x1T, x1B, hc, c1, Wp1, Up1, b1, hn,
                seqs + (size_t)t * oT * 2, oB * 2, nullptr, nullptr, 0);
            short* tmp = hc; hc = hn; hn = tmp;
        }
        // L2 step 0: zero h (clobber hc, free now) + zero c, generic body.
        hipMemsetAsync(hc, 0, HB, stream);
        hipMemsetAsync(c2, 0, CB, stream);
        convlstm_step<64, 3, false, false><<<dim3(512), dim3(NT), SH_L2, stream>>>(
            seqs, oB * 2, hc, c2, Wp2, Up2, b2, hn, nullptr, 0,
            nullptr, nullptr, 0);
        relu_copy<<<dim3(8192), dim3(NTU), 0, stream>>>(hn, out, oB);
        { short* tmp = hc; hc = hn; hn = tmp; }
        for (int t = 1; t < 10; ++t) {
            convlstm_step<64, 3, false, false><<<dim3(512), dim3(NT), SH_L2, stream>>>(
                seqs + (size_t)t * oT * 2, oB * 2, hc, c2, Wp2, Up2, b2, hn,
                nullptr, 0, nullptr, nullptr, 0);
            relu_copy<<<dim3(8192), dim3(NTU), 0, stream>>>(hn, out + (size_t)t * oT, oB);
            short* tmp = hc; hc = hn; hn = tmp;
        }
    }
}

// Round 5
// 2005.334 us; speedup vs baseline: 1.1437x; 1.1437x over previous
//
#include <hip/hip_runtime.h>
#include <cstdint>
#include <cmath>

// ConvLSTM2D x2, B=8 T=10 H=W=64 Cin=32 F=64, split-bf16 MFMA implicit GEMM.
// Round 10: revert R9's XCD remap (regression: occupancy 31->18%, FETCH
// unchanged -> mapping assumption wrong). Back to R8 schedule (1648us), plus:
//  (a) register row-prefetch of the h-plane: next ky's h row is loaded into
//      4 uint4 regs at the TOP of the compute phase (hides ~900cyc HBM/L2
//      latency under ~3.5Kcyc of MFMA); the stage phase becomes a pure
//      ds_write. +16 arch VGPR (84->~100, cap 106 at 3 blk/CU -> no spill).
//  (b) s_setprio(1) around the MFMA cluster (role-diverse CU residency).

#define NT        256   // step-kernel threads (4 waves)
#define NTU       256   // utility-kernel threads
#define RELU_BLKS 256   // relu tail blocks inside fused launch

typedef __attribute__((ext_vector_type(8))) short short8;
typedef __attribute__((ext_vector_type(4))) float f32x4;

__device__ __forceinline__ float hsig(float v) {
    return fminf(fmaxf(fmaf(v, 0.2f, 0.5f), 0.0f), 1.0f);
}

__device__ __forceinline__ short bf16rnd(float f) {
    union { float f; unsigned u; } a; a.f = f;
    return (short)((a.u + 0x7FFFu + ((a.u >> 16) & 1u)) >> 16);
}

__device__ __forceinline__ void split_bf16(float f, short& h, short& l) {
    h = bf16rnd(f);
    union { unsigned u; float f; } b; b.u = ((unsigned)(unsigned short)h) << 16;
    l = bf16rnd(f - b.f);
}

__device__ __forceinline__ float from_bf16(short s) {
    union { unsigned u; float f; } b; b.u = ((unsigned)(unsigned short)s) << 16;
    return b.f;
}

struct BF { uint4 bh[4]; uint4 bl[4]; };   // 4 gates x (hi,lo) fragments

// One ConvLSTM step body. bidx: 8 batch * 64 rows = 0..511; 256 threads,
// wave w handles gate filter-group fg = w. HZ: h_prev/c_state are known
// zero -> skip h staging, h segs, and c read (exact, zero contributes 0).
template<int CINX, int KS, bool WRITE_SEQ, bool HZ>
__device__ __forceinline__ void step_body(
    short* __restrict__ xs, short* __restrict__ hs,
    const short* __restrict__ xp, long xp_bstride,     // shorts
    const short* __restrict__ h_prev,
    float* __restrict__ c_state,
    const short* __restrict__ Wpk,
    const short* __restrict__ Upk,
    const float* __restrict__ bias,
    short* __restrict__ h_next,
    short* __restrict__ seq, long seq_bstride,         // shorts
    int bidx)
{
    constexpr int PAD  = KS / 2;
    constexpr int COLS = 64 + 2 * PAD;
    constexpr int CHX  = CINX / 32;
    constexpr int SEGS = HZ ? CHX : (CHX + 2);  // x chunks (+ 2 h chunks)
    constexpr int PSTX = 2 * CINX + 8;          // shorts per px (x buf)
    constexpr int PSTH = 136;                   // shorts per px (h buf)
    constexpr int VPPX = CINX / 4;              // uint4 per px (x)
    constexpr int KH   = 4;                     // h-plane uint4 per thread

    const int tid  = threadIdx.x;
    const int lane = tid & 63;
    const int fg   = tid >> 6;                 // 0..3 gate filter-group
    const int q8   = ((lane >> 4) & 3) * 8;
    const int batch = bidx >> 6;
    const int y     = bidx & 63;

    const short* xim = xp + (size_t)batch * xp_bstride;
    const short* him = h_prev + (size_t)batch * 4096 * 128;

    // zero LDS buffers (halo stays zero; interior overwritten per ky)
    for (int idx = tid; idx < (COLS * PSTX) / 8; idx += NT) {
        uint4 z; z.x = 0; z.y = 0; z.z = 0; z.w = 0;
        *(uint4*)(xs + idx * 8) = z;
    }
    if constexpr (!HZ) {
        for (int idx = tid; idx < (COLS * PSTH) / 8; idx += NT) {
            uint4 z; z.x = 0; z.y = 0; z.z = 0; z.w = 0;
            *(uint4*)(hs + idx * 8) = z;
        }
    }

    f32x4 acc[4][4];
    #pragma unroll
    for (int g = 0; g < 4; ++g)
        #pragma unroll
        for (int mt = 0; mt < 4; ++mt)
            #pragma unroll
            for (int r = 0; r < 4; ++r) acc[g][mt][r] = 0.0f;

    // B-fragment loader: seg s<CHX -> Wpk chunk s; else Upk chunk s-CHX.
    auto loadB = [&](int ky, int kx, int s) -> BF {
        int tap = ky * KS + kx;
        const short* base;
        if (s < CHX)
            base = Wpk + ((size_t)((tap * CHX + s) * 16 + fg)) * 1024 + lane * 16;
        else
            base = Upk + ((size_t)((tap * 2 + (s - CHX)) * 16 + fg)) * 1024 + lane * 16;
        BF b;
        #pragma unroll
        for (int g = 0; g < 4; ++g) {
            b.bh[g] = *(const uint4*)(base + (size_t)g * 4096);
            b.bl[g] = *(const uint4*)(base + (size_t)g * 4096 + 8);
        }
        return b;
    };

    // h-plane register prefetch: idx = tid + k*NT -> px = (tid>>4)+16k,
    // v = tid&15 (NT=256 is a multiple of 16).
    uint4 hbuf[KH];
    const int hpx0 = tid >> 4;
    const int hv   = tid & 15;
    auto loadh = [&](int yin) {
        const short* hrow = him + (size_t)yin * 64 * 128;
        #pragma unroll
        for (int k = 0; k < KH; ++k)
            hbuf[k] = *(const uint4*)(hrow + (hpx0 + 16 * k) * 128 + hv * 8);
    };
    auto writeh = [&]() {
        #pragma unroll
        for (int k = 0; k < KH; ++k)
            *(uint4*)(hs + (hpx0 + 16 * k + PAD) * PSTH + hv * 8) = hbuf[k];
    };

    const int ky0   = (y < PAD) ? (PAD - y) : 0;
    const int kyend = (64 + PAD - y) < KS ? (64 + PAD - y) : KS;

    BF bcur = loadB(ky0, 0, 0);
    if constexpr (!HZ) loadh(y + ky0 - PAD);    // first row into regs

    for (int ky = ky0; ky < kyend; ++ky) {
        int yin = y + ky - PAD;                     // always in [0,64)
        __syncthreads();                            // prior readers done
        const short* xrow = xim + (size_t)yin * 64 * 2 * CINX;
        for (int idx = tid; idx < 64 * VPPX; idx += NT) {
            int px = idx / VPPX;                    // pow2
            int v  = idx - px * VPPX;
            *(uint4*)(xs + (px + PAD) * PSTX + v * 8)
                = *(const uint4*)(xrow + px * 2 * CINX + v * 8);
        }
        if constexpr (!HZ) writeh();                // h row: regs -> LDS
        __syncthreads();

        // issue next row's h loads NOW; they drain during the MFMA phase
        // (the next barrier's vmcnt(0) finds them complete).
        if constexpr (!HZ) {
            if (ky + 1 < kyend) loadh(yin + 1);
        }

        #pragma unroll
        for (int kx = 0; kx < KS; ++kx) {
            #pragma unroll
            for (int s = 0; s < SEGS; ++s) {
                // next (s,kx,ky) in iteration order; ky clamped (extra load
                // of a valid address on the final step, harmless)
                int ns = s + 1, nkx = kx, nky = ky;
                if (ns == SEGS) { ns = 0; ++nkx; }
                if (nkx == KS)  { nkx = 0; ++nky; }
                nky = (nky < kyend) ? nky : ky;
                BF bnxt = loadB(nky, nkx, ns);      // prefetch (global)

                short8 ah[4], al[4];
                #pragma unroll
                for (int mt = 0; mt < 4; ++mt) {
                    int col = mt * 16 + (lane & 15) + kx;
                    const short* p = (s < CHX)
                        ? (xs + col * PSTX + s * 32 + q8)
                        : (hs + col * PSTH + (s - CHX) * 32 + q8);
                    int lo = (s < CHX) ? CINX : 64;
                    ah[mt] = *(const short8*)p;
                    al[mt] = *(const short8*)(p + lo);
                }
                __builtin_amdgcn_s_setprio(1);
                #pragma unroll
                for (int g = 0; g < 4; ++g) {
                    short8 bh = *(const short8*)&bcur.bh[g];
                    short8 bl = *(const short8*)&bcur.bl[g];
                    #pragma unroll
                    for (int mt = 0; mt < 4; ++mt) {
                        acc[g][mt] = __builtin_amdgcn_mfma_f32_16x16x32_bf16(
                            ah[mt], bh, acc[g][mt], 0, 0, 0);
                        acc[g][mt] = __builtin_amdgcn_mfma_f32_16x16x32_bf16(
                            al[mt], bh, acc[g][mt], 0, 0, 0);
                        acc[g][mt] = __builtin_amdgcn_mfma_f32_16x16x32_bf16(
                            ah[mt], bl, acc[g][mt], 0, 0, 0);
                    }
                }
                __builtin_amdgcn_s_setprio(0);
                bcur = bnxt;
            }
        }
    }

    // ---- epilogue (layout verified R2/R3) ----
    const int fl = fg * 16 + (lane & 15);
    const float b_i = bias[fl];
    const float b_f = bias[64 + fl];
    const float b_c = bias[128 + fl];
    const float b_o = bias[192 + fl];
    const int q = (lane >> 4) & 3;

    const long pixbase = (long)batch * 4096 + (long)y * 64;
    const long cb = pixbase * 64 + fl;
    const long sb = (long)batch * seq_bstride + ((long)y * 64) * 128 + fl;

    #pragma unroll
    for (int mt = 0; mt < 4; ++mt) {
        #pragma unroll
        for (int r = 0; r < 4; ++r) {
            int col = mt * 16 + q * 4 + r;
            long cidx = cb + (long)col * 64;
            float zi = acc[0][mt][r] + b_i;
            float zf = acc[1][mt][r] + b_f;
            float zc = acc[2][mt][r] + b_c;
            float zo = acc[3][mt][r] + b_o;
            float ig = hsig(zi);
            float fgt = hsig(zf);
            float og = hsig(zo);
            float cp = HZ ? 0.0f : c_state[cidx];
            float cn = fgt * cp + ig * tanhf(zc);
            float hn = og * tanhf(cn);
            c_state[cidx] = cn;

            short hh, hl;
            split_bf16(hn, hh, hl);
            long hoff = (pixbase + col) * 128 + fl;
            h_next[hoff]      = hh;
            h_next[hoff + 64] = hl;
            if (WRITE_SEQ) {
                bool pos = hn > 0.0f;
                seq[sb + (long)col * 128]      = pos ? hh : (short)0;
                seq[sb + (long)col * 128 + 64] = pos ? hl : (short)0;
            }
        }
    }
}

// Standalone step kernel (edge steps + serial fallback).
template<int CINX, int KS, bool WRITE_SEQ, bool HZ>
__global__ __launch_bounds__(NT, 2)
void convlstm_step(
    const short* __restrict__ xp, long xp_bstride,
    const short* __restrict__ h_prev,
    float* __restrict__ c_state,
    const short* __restrict__ Wpk,
    const short* __restrict__ Upk,
    const float* __restrict__ bias,
    short* __restrict__ h_next,
    short* __restrict__ seq, long seq_bstride)
{
    extern __shared__ __align__(16) short smem[];
    constexpr int PAD  = KS / 2;
    constexpr int COLS = 64 + 2 * PAD;
    constexpr int PSTX = 2 * CINX + 8;
    step_body<CINX, KS, WRITE_SEQ, HZ>(
        smem, smem + COLS * PSTX,
        xp, xp_bstride, h_prev, c_state, Wpk, Upk, bias,
        h_next, seq, seq_bstride, (int)blockIdx.x);
}

// Fused launch: blocks 0..511 run L1 step t, 512..1023 run L2 step t-1
// (independent: L2 reads seq[t-1] written by the PREVIOUS launch),
// 1024..1024+RELU_BLKS-1 stream relu(out[t-2]) from the L2 h-state of
// step t-2 (== h2p of this launch; nobody writes it this launch).
// launch_bounds (256,3): 170-reg cap -> ~100 arch + 64 acc fits, NO spill.
__global__ __launch_bounds__(NT, 3)
void convlstm_fused(
    const short* __restrict__ x1, long x1_bs,
    const short* __restrict__ h1p, float* __restrict__ c1,
    const short* __restrict__ Wp1, const short* __restrict__ Up1,
    const float* __restrict__ b1,
    short* __restrict__ h1n, short* __restrict__ seq1, long seq1_bs,
    const short* __restrict__ x2, long x2_bs,
    const short* __restrict__ h2p, float* __restrict__ c2,
    const short* __restrict__ Wp2, const short* __restrict__ Up2,
    const float* __restrict__ b2,
    short* __restrict__ h2n,
    const short* __restrict__ relu_src, float* __restrict__ relu_dst,
    long out_bstride)
{
    extern __shared__ __align__(16) short smem[];
    const int b = (int)blockIdx.x;
    if (b < 512) {
        step_body<32, 5, true, false>(
            smem, smem + 68 * 72,
            x1, x1_bs, h1p, c1, Wp1, Up1, b1, h1n, seq1, seq1_bs, b);
    } else if (b < 1024) {
        step_body<64, 3, false, false>(
            smem, smem + 66 * 136,
            x2, x2_bs, h2p, c2, Wp2, Up2, b2, h2n, nullptr, 0, b - 512);
    } else {
        if (relu_dst == nullptr) return;
        long i = (long)(b - 1024) * NT + threadIdx.x;
        for (; i < (1L << 21); i += (long)RELU_BLKS * NT) {
            long pix = i >> 6;
            int  c   = (int)(i & 63);
            float f = from_bf16(relu_src[pix * 128 + c])
                    + from_bf16(relu_src[pix * 128 + 64 + c]);
            long bb = pix >> 12;
            relu_dst[bb * out_bstride + (pix & 4095) * 64 + c] = fmaxf(f, 0.0f);
        }
    }
}

// fp32 x [Npix][32] -> hi/lo planes [Npix]{32 hi,32 lo}. One thread = 4 ch.
__global__ void convert_planes32(const float4* __restrict__ src,
                                 unsigned* __restrict__ dst, int n4)
{
    int t = blockIdx.x * NTU + threadIdx.x;
    if (t >= n4) return;
    int pix = t >> 3;
    int c4  = t & 7;
    float4 v = src[t];
    short h0, l0, h1, l1, h2, l2, h3, l3;
    split_bf16(v.x, h0, l0);
    split_bf16(v.y, h1, l1);
    split_bf16(v.z, h2, l2);
    split_bf16(v.w, h3, l3);
    unsigned* p = dst + (size_t)pix * 32;
    p[c4 * 2]      = (unsigned)(unsigned short)h0 | ((unsigned)(unsigned short)h1 << 16);
    p[c4 * 2 + 1]  = (unsigned)(unsigned short)h2 | ((unsigned)(unsigned short)h3 << 16);
    p[16 + c4 * 2]     = (unsigned)(unsigned short)l0 | ((unsigned)(unsigned short)l1 << 16);
    p[16 + c4 * 2 + 1] = (unsigned)(unsigned short)l2 | ((unsigned)(unsigned short)l3 << 16);
}

// Repack fp32 weights [KS,KS,CIN,256] -> B-fragment hi/lo layout (verified R2).
__global__ void repack(const float* __restrict__ src, short* __restrict__ dst,
                       int KS, int CH)
{
    int total = KS * KS * CH * 16 * 64;
    int t = blockIdx.x * NTU + threadIdx.x;
    if (t >= total) return;
    int u = t >> 6, lane = t & 63;
    int tap = u / (CH * 16);
    int rem = u - tap * (CH * 16);
    int ch = rem >> 4;
    int gfg = rem & 15;
    int g = gfg >> 2, fgp = gfg & 3;
    int CIN = CH * 32;
    int n = lane & 15, qq = lane >> 4;
    short* d = dst + (size_t)u * 1024 + lane * 16;
    int gc = g * 64 + fgp * 16 + n;
    for (int j = 0; j < 8; ++j) {
        int c = ch * 32 + qq * 8 + j;
        float w = src[((size_t)tap * CIN + c) * 256 + gc];
        short h, l;
        split_bf16(w, h, l);
        d[j] = h;
        d[8 + j] = l;
    }
}

// out[b, t, pix, c] = relu(hi/lo planes h)
__global__ void relu_copy(const short* __restrict__ hp, float* __restrict__ out,
                          long out_bstride)
{
    long i = (long)blockIdx.x * NTU + threadIdx.x;   // 0 .. 2^21-1
    long pix = i >> 6;
    int c = (int)(i & 63);
    float f = from_bf16(hp[pix * 128 + c]) + from_bf16(hp[pix * 128 + 64 + c]);
    long b = pix >> 12;
    long within = (pix & 4095) * 64 + c;
    out[b * out_bstride + within] = fmaxf(f, 0.0f);
}

extern "C" void kernel_launch(void* const* d_in, const int* in_sizes, int n_in,
                              void* d_out, int out_size, void* d_ws, size_t ws_size,
                              hipStream_t stream) {
    const float* x   = (const float*)d_in[0];   // [8,10,64,64,32]
    const float* Wk1 = (const float*)d_in[1];   // [5,5,32,256]
    const float* Uk1 = (const float*)d_in[2];   // [5,5,64,256]
    const float* b1  = (const float*)d_in[3];   // [256]
    const float* Wk2 = (const float*)d_in[4];   // [3,3,64,256]
    const float* Uk2 = (const float*)d_in[5];   // [3,3,64,256]
    const float* b2  = (const float*)d_in[6];   // [256]
    float* out = (float*)d_out;                 // [8,10,64,64,64]

    const long S  = (long)8 * 64 * 64 * 64;     // 2,097,152 state elems
    const long oT = (long)64 * 64 * 64;         // out t-stride (floats)
    const long oB = 10 * oT;                    // out batch-stride (floats)
    const long x1T = (long)4096 * 64;           // x-plane t-stride (shorts)
    const long x1B = 10 * x1T;                  // x-plane batch-stride (shorts)

    // sizes (bytes)
    const size_t HB  = (size_t)4 * S;                 // one h plane buffer
    const size_t CB  = (size_t)4 * S;                 // one c buffer
    const size_t W1B = (size_t)25 * 1 * 16 * 1024 * 2;
    const size_t U1B = (size_t)25 * 2 * 16 * 1024 * 2;
    const size_t W2B = (size_t)9 * 2 * 16 * 1024 * 2;
    const size_t U2B = (size_t)9 * 2 * 16 * 1024 * 2;
    const size_t XPB = (size_t)8 * x1B * 2;           // FULL 8-batch x planes
    const size_t need_ov = 4 * HB + 2 * CB + W1B + U1B + W2B + U2B + XPB;
    const bool ov = (ws_size >= need_ov);

    short* h1a = (short*)d_ws;
    short* h1b = h1a + 2 * S;
    short *h2a, *h2b;
    float *c1, *c2;
    short* Wp1;
    if (ov) {
        h2a = h1b + 2 * S;
        h2b = h2a + 2 * S;
        c1  = (float*)(h2b + 2 * S);
        c2  = c1 + S;
        Wp1 = (short*)(c2 + S);
    } else {
        h2a = h1a; h2b = h1b;               // serial reuse
        c1  = (float*)(h1b + 2 * S);
        c2  = c1;
        Wp1 = (short*)(c1 + S);
    }
    short* Up1 = Wp1 + 25 * 1 * 16 * 1024;
    short* Wp2 = Up1 + 25 * 2 * 16 * 1024;
    short* Up2 = Wp2 + 9 * 2 * 16 * 1024;
    short* x1p = Up2 + 9 * 2 * 16 * 1024;   // x planes: 8*10*4096*64 shorts

    {
        int n4 = 8 * 10 * 4096 * 8;
        convert_planes32<<<dim3((n4 + NTU - 1) / NTU), dim3(NTU), 0, stream>>>(
            (const float4*)x, (unsigned*)x1p, n4);
    }
    repack<<<dim3((25 * 1 * 16 * 64 + NTU - 1) / NTU), dim3(NTU), 0, stream>>>(Wk1, Wp1, 5, 1);
    repack<<<dim3((25 * 2 * 16 * 64 + NTU - 1) / NTU), dim3(NTU), 0, stream>>>(Uk1, Up1, 5, 2);
    repack<<<dim3((9 * 2 * 16 * 64 + NTU - 1) / NTU), dim3(NTU), 0, stream>>>(Wk2, Wp2, 3, 2);
    repack<<<dim3((9 * 2 * 16 * 64 + NTU - 1) / NTU), dim3(NTU), 0, stream>>>(Uk2, Up2, 3, 2);

    short* seqs = (short*)d_out;            // seq planes live in d_out slots

    // dynamic LDS sizes (bytes)
    const size_t SH_L1HZ = (size_t)(68 * 72) * 2;                 //  9,792
    const size_t SH_L1   = (size_t)(68 * 72 + 68 * 136) * 2;      // 28,288
    const size_t SH_L2   = (size_t)(66 * 136) * 4;                // 35,904
    const size_t SH_F    = SH_L2;

    if (ov) {
        // zero L2 initial state (h2a, c2); L1 step 0 handles its own zeros
        // via the HZ body (writes c1/h1b fully, so no memset needed for L1).
        hipMemsetAsync(h2a, 0, HB, stream);
        hipMemsetAsync(c2, 0, CB, stream);

        // L1 step 0 (h==0): x-conv only, writes h1b + seq[0]
        convlstm_step<32, 5, true, true><<<dim3(512), dim3(NT), SH_L1HZ, stream>>>(
            x1p, x1B, h1a, c1, Wp1, Up1, b1, h1b, seqs, oB * 2);

        short* hc1 = h1b; short* hn1 = h1a;
        short* hc2 = h2a; short* hn2 = h2b;
        for (int t = 1; t < 10; ++t) {
            const short* x2 = seqs + (size_t)(t - 1) * oT * 2;
            float* rdst = (t >= 2) ? (out + (size_t)(t - 2) * oT) : (float*)nullptr;
            convlstm_fused<<<dim3(1024 + RELU_BLKS), dim3(NT), SH_F, stream>>>(
                x1p + (size_t)t * x1T, x1B, hc1, c1, Wp1, Up1, b1, hn1,
                seqs + (size_t)t * oT * 2, oB * 2,
                x2, oB * 2, hc2, c2, Wp2, Up2, b2, hn2,
                hc2, rdst, oB);
            short* tmp;
            tmp = hc1; hc1 = hn1; hn1 = tmp;
            tmp = hc2; hc2 = hn2; hn2 = tmp;
        }
        // L2 step 9 (standalone), then the two remaining relu copies.
        convlstm_step<64, 3, false, false><<<dim3(512), dim3(NT), SH_L2, stream>>>(
            seqs + (size_t)9 * oT * 2, oB * 2, hc2, c2, Wp2, Up2, b2, hn2,
            nullptr, 0);
        relu_copy<<<dim3(8192), dim3(NTU), 0, stream>>>(hc2, out + 8 * oT, oB);
        relu_copy<<<dim3(8192), dim3(NTU), 0, stream>>>(hn2, out + 9 * oT, oB);
    } else {
        // ---- serial fallback (R5-verified footprint; HZ for L1 step 0) ----
        convlstm_step<32, 5, true, true><<<dim3(512), dim3(NT), SH_L1HZ, stream>>>(
            x1p, x1B, h1a, c1, Wp1, Up1, b1, h1b, seqs, oB * 2);
        short* hc = h1b; short* hn = h1a;
        for (int t = 1; t < 10; ++t) {
            convlstm_step<32, 5, true, false><<<dim3(512), dim3(NT), SH_L1, stream>>>(
                x1p + (size_t)t * x1T, x1B, hc, c1, Wp1, Up1, b1, hn,
                seqs + (size_t)t * oT * 2, oB * 2);
            short* tmp = hc; hc = hn; hn = tmp;
        }
        // L2 step 0: zero h (clobber hc, free now) + zero c, generic body.
        hipMemsetAsync(hc, 0, HB, stream);
        hipMemsetAsync(c2, 0, CB, stream);
        convlstm_step<64, 3, false, false><<<dim3(512), dim3(NT), SH_L2, stream>>>(
            seqs, oB * 2, hc, c2, Wp2, Up2, b2, hn, nullptr, 0);
        relu_copy<<<dim3(8192), dim3(NTU), 0, stream>>>(hn, out, oB);
        { short* tmp = hc; hc = hn; hn = tmp; }
        for (int t = 1; t < 10; ++t) {
            convlstm_step<64, 3, false, false><<<dim3(512), dim3(NT), SH_L2, stream>>>(
                seqs + (size_t)t * oT * 2, oB * 2, hc, c2, Wp2, Up2, b2, hn,
                nullptr, 0);
            relu_copy<<<dim3(8192), dim3(NTU), 0, stream>>>(hn, out + (size_t)t * oT, oB);
            short* tmp = hc; hc = hn; hn = tmp;
        }
    }
}

// Round 6
// 1621.118 us; speedup vs baseline: 1.4148x; 1.2370x over previous
//
#include <hip/hip_runtime.h>
#include <cstdint>
#include <cmath>

// ConvLSTM2D x2, B=8 T=10 H=W=64 Cin=32 F=64, split-bf16 MFMA implicit GEMM.
// Round 11: revert R10's h-register-prefetch (spilled: FETCH 98->218MB,
// WRITE 48->248MB; zero VGPR headroom at (256,3) — twice confirmed).
// Back to the verified R8 structure (1648us), ONE register-neutral change:
// seq planes move from d_out to two rotating 8MB ws buffers, and the L2
// epilogue writes relu(h) straight to out (value already in register).
// Deletes the relu tail blocks, both relu_copy launches, and the step-9
// h_next write. K-loop untouched.

#define NT        256   // step-kernel threads (4 waves)
#define NTU       256   // utility-kernel threads

typedef __attribute__((ext_vector_type(8))) short short8;
typedef __attribute__((ext_vector_type(4))) float f32x4;

__device__ __forceinline__ float hsig(float v) {
    return fminf(fmaxf(fmaf(v, 0.2f, 0.5f), 0.0f), 1.0f);
}

__device__ __forceinline__ short bf16rnd(float f) {
    union { float f; unsigned u; } a; a.f = f;
    return (short)((a.u + 0x7FFFu + ((a.u >> 16) & 1u)) >> 16);
}

__device__ __forceinline__ void split_bf16(float f, short& h, short& l) {
    h = bf16rnd(f);
    union { unsigned u; float f; } b; b.u = ((unsigned)(unsigned short)h) << 16;
    l = bf16rnd(f - b.f);
}

__device__ __forceinline__ float from_bf16(short s) {
    union { unsigned u; float f; } b; b.u = ((unsigned)(unsigned short)s) << 16;
    return b.f;
}

struct BF { uint4 bh[4]; uint4 bl[4]; };   // 4 gates x (hi,lo) fragments

// One ConvLSTM step body. bidx: 8 batch * 64 rows = 0..511; 256 threads,
// wave w handles gate filter-group fg = w. HZ: h_prev/c_state are known
// zero -> skip h staging, h segs, and c read (exact, zero contributes 0).
// h_next may be null (state not needed). outf non-null -> also store
// relu(h) as floats to outf (batch stride outf_bs, [pix][64] layout).
template<int CINX, int KS, bool WRITE_SEQ, bool HZ>
__device__ __forceinline__ void step_body(
    short* __restrict__ xs, short* __restrict__ hs,
    const short* __restrict__ xp, long xp_bstride,     // shorts
    const short* __restrict__ h_prev,
    float* __restrict__ c_state,
    const short* __restrict__ Wpk,
    const short* __restrict__ Upk,
    const float* __restrict__ bias,
    short* __restrict__ h_next,
    short* __restrict__ seq, long seq_bstride,         // shorts
    float* __restrict__ outf, long outf_bs,            // floats
    int bidx)
{
    constexpr int PAD  = KS / 2;
    constexpr int COLS = 64 + 2 * PAD;
    constexpr int CHX  = CINX / 32;
    constexpr int SEGS = HZ ? CHX : (CHX + 2);  // x chunks (+ 2 h chunks)
    constexpr int PSTX = 2 * CINX + 8;          // shorts per px (x buf)
    constexpr int PSTH = 136;                   // shorts per px (h buf)
    constexpr int VPPX = CINX / 4;              // uint4 per px (x)

    const int tid  = threadIdx.x;
    const int lane = tid & 63;
    const int fg   = tid >> 6;                 // 0..3 gate filter-group
    const int q8   = ((lane >> 4) & 3) * 8;
    const int batch = bidx >> 6;
    const int y     = bidx & 63;

    const short* xim = xp + (size_t)batch * xp_bstride;
    const short* him = h_prev + (size_t)batch * 4096 * 128;

    // zero LDS buffers (halo stays zero; interior overwritten per ky)
    for (int idx = tid; idx < (COLS * PSTX) / 8; idx += NT) {
        uint4 z; z.x = 0; z.y = 0; z.z = 0; z.w = 0;
        *(uint4*)(xs + idx * 8) = z;
    }
    if constexpr (!HZ) {
        for (int idx = tid; idx < (COLS * PSTH) / 8; idx += NT) {
            uint4 z; z.x = 0; z.y = 0; z.z = 0; z.w = 0;
            *(uint4*)(hs + idx * 8) = z;
        }
    }

    f32x4 acc[4][4];
    #pragma unroll
    for (int g = 0; g < 4; ++g)
        #pragma unroll
        for (int mt = 0; mt < 4; ++mt)
            #pragma unroll
            for (int r = 0; r < 4; ++r) acc[g][mt][r] = 0.0f;

    // B-fragment loader: seg s<CHX -> Wpk chunk s; else Upk chunk s-CHX.
    auto loadB = [&](int ky, int kx, int s) -> BF {
        int tap = ky * KS + kx;
        const short* base;
        if (s < CHX)
            base = Wpk + ((size_t)((tap * CHX + s) * 16 + fg)) * 1024 + lane * 16;
        else
            base = Upk + ((size_t)((tap * 2 + (s - CHX)) * 16 + fg)) * 1024 + lane * 16;
        BF b;
        #pragma unroll
        for (int g = 0; g < 4; ++g) {
            b.bh[g] = *(const uint4*)(base + (size_t)g * 4096);
            b.bl[g] = *(const uint4*)(base + (size_t)g * 4096 + 8);
        }
        return b;
    };

    const int ky0   = (y < PAD) ? (PAD - y) : 0;
    const int kyend = (64 + PAD - y) < KS ? (64 + PAD - y) : KS;

    BF bcur = loadB(ky0, 0, 0);

    for (int ky = ky0; ky < kyend; ++ky) {
        int yin = y + ky - PAD;                     // always in [0,64)
        __syncthreads();                            // prior readers done
        const short* xrow = xim + (size_t)yin * 64 * 2 * CINX;
        for (int idx = tid; idx < 64 * VPPX; idx += NT) {
            int px = idx / VPPX;                    // pow2
            int v  = idx - px * VPPX;
            *(uint4*)(xs + (px + PAD) * PSTX + v * 8)
                = *(const uint4*)(xrow + px * 2 * CINX + v * 8);
        }
        if constexpr (!HZ) {
            const short* hrow = him + (size_t)yin * 64 * 128;
            for (int idx = tid; idx < 64 * 16; idx += NT) {
                int px = idx >> 4;
                int v  = idx & 15;
                *(uint4*)(hs + (px + PAD) * PSTH + v * 8)
                    = *(const uint4*)(hrow + px * 128 + v * 8);
            }
        }
        __syncthreads();

        #pragma unroll
        for (int kx = 0; kx < KS; ++kx) {
            #pragma unroll
            for (int s = 0; s < SEGS; ++s) {
                // next (s,kx,ky) in iteration order; ky clamped (extra load
                // of a valid address on the final step, harmless)
                int ns = s + 1, nkx = kx, nky = ky;
                if (ns == SEGS) { ns = 0; ++nkx; }
                if (nkx == KS)  { nkx = 0; ++nky; }
                nky = (nky < kyend) ? nky : ky;
                BF bnxt = loadB(nky, nkx, ns);      // prefetch (global)

                short8 ah[4], al[4];
                #pragma unroll
                for (int mt = 0; mt < 4; ++mt) {
                    int col = mt * 16 + (lane & 15) + kx;
                    const short* p = (s < CHX)
                        ? (xs + col * PSTX + s * 32 + q8)
                        : (hs + col * PSTH + (s - CHX) * 32 + q8);
                    int lo = (s < CHX) ? CINX : 64;
                    ah[mt] = *(const short8*)p;
                    al[mt] = *(const short8*)(p + lo);
                }
                #pragma unroll
                for (int g = 0; g < 4; ++g) {
                    short8 bh = *(const short8*)&bcur.bh[g];
                    short8 bl = *(const short8*)&bcur.bl[g];
                    #pragma unroll
                    for (int mt = 0; mt < 4; ++mt) {
                        acc[g][mt] = __builtin_amdgcn_mfma_f32_16x16x32_bf16(
                            ah[mt], bh, acc[g][mt], 0, 0, 0);
                        acc[g][mt] = __builtin_amdgcn_mfma_f32_16x16x32_bf16(
                            al[mt], bh, acc[g][mt], 0, 0, 0);
                        acc[g][mt] = __builtin_amdgcn_mfma_f32_16x16x32_bf16(
                            ah[mt], bl, acc[g][mt], 0, 0, 0);
                    }
                }
                bcur = bnxt;
            }
        }
    }

    // ---- epilogue (layout verified R2/R3) ----
    const int fl = fg * 16 + (lane & 15);
    const float b_i = bias[fl];
    const float b_f = bias[64 + fl];
    const float b_c = bias[128 + fl];
    const float b_o = bias[192 + fl];
    const int q = (lane >> 4) & 3;

    const long pixbase = (long)batch * 4096 + (long)y * 64;
    const long cb = pixbase * 64 + fl;
    const long sb = (long)batch * seq_bstride + ((long)y * 64) * 128 + fl;
    const long ob = (long)batch * outf_bs + ((long)y * 64) * 64 + fl;

    #pragma unroll
    for (int mt = 0; mt < 4; ++mt) {
        #pragma unroll
        for (int r = 0; r < 4; ++r) {
            int col = mt * 16 + q * 4 + r;
            long cidx = cb + (long)col * 64;
            float zi = acc[0][mt][r] + b_i;
            float zf = acc[1][mt][r] + b_f;
            float zc = acc[2][mt][r] + b_c;
            float zo = acc[3][mt][r] + b_o;
            float ig = hsig(zi);
            float fgt = hsig(zf);
            float og = hsig(zo);
            float cp = HZ ? 0.0f : c_state[cidx];
            float cn = fgt * cp + ig * tanhf(zc);
            float hn = og * tanhf(cn);
            c_state[cidx] = cn;

            if (h_next) {
                short hh, hl;
                split_bf16(hn, hh, hl);
                long hoff = (pixbase + col) * 128 + fl;
                h_next[hoff]      = hh;
                h_next[hoff + 64] = hl;
            }
            if (WRITE_SEQ) {
                short hh, hl;
                split_bf16(hn, hh, hl);
                bool pos = hn > 0.0f;
                seq[sb + (long)col * 128]      = pos ? hh : (short)0;
                seq[sb + (long)col * 128 + 64] = pos ? hl : (short)0;
            }
            if (outf)
                outf[ob + (long)col * 64] = fmaxf(hn, 0.0f);
        }
    }
}

// Standalone step kernel (edge steps + serial fallback).
template<int CINX, int KS, bool WRITE_SEQ, bool HZ>
__global__ __launch_bounds__(NT, 2)
void convlstm_step(
    const short* __restrict__ xp, long xp_bstride,
    const short* __restrict__ h_prev,
    float* __restrict__ c_state,
    const short* __restrict__ Wpk,
    const short* __restrict__ Upk,
    const float* __restrict__ bias,
    short* __restrict__ h_next,
    short* __restrict__ seq, long seq_bstride,
    float* __restrict__ outf, long outf_bs)
{
    extern __shared__ __align__(16) short smem[];
    constexpr int PAD  = KS / 2;
    constexpr int COLS = 64 + 2 * PAD;
    constexpr int PSTX = 2 * CINX + 8;
    step_body<CINX, KS, WRITE_SEQ, HZ>(
        smem, smem + COLS * PSTX,
        xp, xp_bstride, h_prev, c_state, Wpk, Upk, bias,
        h_next, seq, seq_bstride, outf, outf_bs, (int)blockIdx.x);
}

// Fused launch: blocks 0..511 run L1 step t, 512..1023 run L2 step t-1
// (independent: L2 reads ws seq buffer written by the PREVIOUS launch).
// L2 epilogue writes relu(h) directly to out[t-1] (seq no longer aliases
// d_out, so no race with halo readers of the seq planes).
// launch_bounds (256,3): 170-reg cap -> 84 arch + 64 acc fits, NO spill.
__global__ __launch_bounds__(NT, 3)
void convlstm_fused(
    const short* __restrict__ x1, long x1_bs,
    const short* __restrict__ h1p, float* __restrict__ c1,
    const short* __restrict__ Wp1, const short* __restrict__ Up1,
    const float* __restrict__ b1,
    short* __restrict__ h1n, short* __restrict__ seq1, long seq1_bs,
    const short* __restrict__ x2, long x2_bs,
    const short* __restrict__ h2p, float* __restrict__ c2,
    const short* __restrict__ Wp2, const short* __restrict__ Up2,
    const float* __restrict__ b2,
    short* __restrict__ h2n,
    float* __restrict__ outf2, long outf2_bs)
{
    extern __shared__ __align__(16) short smem[];
    const int b = (int)blockIdx.x;
    if (b < 512) {
        step_body<32, 5, true, false>(
            smem, smem + 68 * 72,
            x1, x1_bs, h1p, c1, Wp1, Up1, b1, h1n, seq1, seq1_bs,
            nullptr, 0, b);
    } else {
        step_body<64, 3, false, false>(
            smem, smem + 66 * 136,
            x2, x2_bs, h2p, c2, Wp2, Up2, b2, h2n, nullptr, 0,
            outf2, outf2_bs, b - 512);
    }
}

// fp32 x [Npix][32] -> hi/lo planes [Npix]{32 hi,32 lo}. One thread = 4 ch.
__global__ void convert_planes32(const float4* __restrict__ src,
                                 unsigned* __restrict__ dst, int n4)
{
    int t = blockIdx.x * NTU + threadIdx.x;
    if (t >= n4) return;
    int pix = t >> 3;
    int c4  = t & 7;
    float4 v = src[t];
    short h0, l0, h1, l1, h2, l2, h3, l3;
    split_bf16(v.x, h0, l0);
    split_bf16(v.y, h1, l1);
    split_bf16(v.z, h2, l2);
    split_bf16(v.w, h3, l3);
    unsigned* p = dst + (size_t)pix * 32;
    p[c4 * 2]      = (unsigned)(unsigned short)h0 | ((unsigned)(unsigned short)h1 << 16);
    p[c4 * 2 + 1]  = (unsigned)(unsigned short)h2 | ((unsigned)(unsigned short)h3 << 16);
    p[16 + c4 * 2]     = (unsigned)(unsigned short)l0 | ((unsigned)(unsigned short)l1 << 16);
    p[16 + c4 * 2 + 1] = (unsigned)(unsigned short)l2 | ((unsigned)(unsigned short)l3 << 16);
}

// Repack fp32 weights [KS,KS,CIN,256] -> B-fragment hi/lo layout (verified R2).
__global__ void repack(const float* __restrict__ src, short* __restrict__ dst,
                       int KS, int CH)
{
    int total = KS * KS * CH * 16 * 64;
    int t = blockIdx.x * NTU + threadIdx.x;
    if (t >= total) return;
    int u = t >> 6, lane = t & 63;
    int tap = u / (CH * 16);
    int rem = u - tap * (CH * 16);
    int ch = rem >> 4;
    int gfg = rem & 15;
    int g = gfg >> 2, fgp = gfg & 3;
    int CIN = CH * 32;
    int n = lane & 15, qq = lane >> 4;
    short* d = dst + (size_t)u * 1024 + lane * 16;
    int gc = g * 64 + fgp * 16 + n;
    for (int j = 0; j < 8; ++j) {
        int c = ch * 32 + qq * 8 + j;
        float w = src[((size_t)tap * CIN + c) * 256 + gc];
        short h, l;
        split_bf16(w, h, l);
        d[j] = h;
        d[8 + j] = l;
    }
}

// out[b, t, pix, c] = relu(hi/lo planes h)   (serial fallback only)
__global__ void relu_copy(const short* __restrict__ hp, float* __restrict__ out,
                          long out_bstride)
{
    long i = (long)blockIdx.x * NTU + threadIdx.x;   // 0 .. 2^21-1
    long pix = i >> 6;
    int c = (int)(i & 63);
    float f = from_bf16(hp[pix * 128 + c]) + from_bf16(hp[pix * 128 + 64 + c]);
    long b = pix >> 12;
    long within = (pix & 4095) * 64 + c;
    out[b * out_bstride + within] = fmaxf(f, 0.0f);
}

extern "C" void kernel_launch(void* const* d_in, const int* in_sizes, int n_in,
                              void* d_out, int out_size, void* d_ws, size_t ws_size,
                              hipStream_t stream) {
    const float* x   = (const float*)d_in[0];   // [8,10,64,64,32]
    const float* Wk1 = (const float*)d_in[1];   // [5,5,32,256]
    const float* Uk1 = (const float*)d_in[2];   // [5,5,64,256]
    const float* b1  = (const float*)d_in[3];   // [256]
    const float* Wk2 = (const float*)d_in[4];   // [3,3,64,256]
    const float* Uk2 = (const float*)d_in[5];   // [3,3,64,256]
    const float* b2  = (const float*)d_in[6];   // [256]
    float* out = (float*)d_out;                 // [8,10,64,64,64]

    const long S  = (long)8 * 64 * 64 * 64;     // 2,097,152 state elems
    const long oT = (long)64 * 64 * 64;         // out t-stride (floats)
    const long oB = 10 * oT;                    // out batch-stride (floats)
    const long x1T = (long)4096 * 64;           // x-plane t-stride (shorts)
    const long x1B = 10 * x1T;                  // x-plane batch-stride (shorts)
    const long sqB = (long)4096 * 128;          // ws seq batch-stride (shorts)

    // sizes (bytes)
    const size_t HB  = (size_t)4 * S;                 // one h/seq plane buffer
    const size_t CB  = (size_t)4 * S;                 // one c buffer
    const size_t W1B = (size_t)25 * 1 * 16 * 1024 * 2;
    const size_t U1B = (size_t)25 * 2 * 16 * 1024 * 2;
    const size_t W2B = (size_t)9 * 2 * 16 * 1024 * 2;
    const size_t U2B = (size_t)9 * 2 * 16 * 1024 * 2;
    const size_t XPB = (size_t)8 * x1B * 2;           // FULL 8-batch x planes
    const size_t need_ov = 6 * HB + 2 * CB + W1B + U1B + W2B + U2B + XPB;
    const bool ov = (ws_size >= need_ov);

    short* h1a = (short*)d_ws;
    short* h1b = h1a + 2 * S;
    short *h2a, *h2b;
    float *c1, *c2;
    short* Wp1;
    if (ov) {
        h2a = h1b + 2 * S;
        h2b = h2a + 2 * S;
        c1  = (float*)(h2b + 2 * S);
        c2  = c1 + S;
        Wp1 = (short*)(c2 + S);
    } else {
        h2a = h1a; h2b = h1b;               // serial reuse
        c1  = (float*)(h1b + 2 * S);
        c2  = c1;
        Wp1 = (short*)(c1 + S);
    }
    short* Up1 = Wp1 + 25 * 1 * 16 * 1024;
    short* Wp2 = Up1 + 25 * 2 * 16 * 1024;
    short* Up2 = Wp2 + 9 * 2 * 16 * 1024;
    short* x1p = Up2 + 9 * 2 * 16 * 1024;   // x planes: 8*10*4096*64 shorts
    short* sqA = x1p + 8 * x1B;             // ws seq buffers (ov only)
    short* sqB_ = sqA + 2 * S;

    {
        int n4 = 8 * 10 * 4096 * 8;
        convert_planes32<<<dim3((n4 + NTU - 1) / NTU), dim3(NTU), 0, stream>>>(
            (const float4*)x, (unsigned*)x1p, n4);
    }
    repack<<<dim3((25 * 1 * 16 * 64 + NTU - 1) / NTU), dim3(NTU), 0, stream>>>(Wk1, Wp1, 5, 1);
    repack<<<dim3((25 * 2 * 16 * 64 + NTU - 1) / NTU), dim3(NTU), 0, stream>>>(Uk1, Up1, 5, 2);
    repack<<<dim3((9 * 2 * 16 * 64 + NTU - 1) / NTU), dim3(NTU), 0, stream>>>(Wk2, Wp2, 3, 2);
    repack<<<dim3((9 * 2 * 16 * 64 + NTU - 1) / NTU), dim3(NTU), 0, stream>>>(Uk2, Up2, 3, 2);

    // dynamic LDS sizes (bytes)
    const size_t SH_L1HZ = (size_t)(68 * 72) * 2;                 //  9,792
    const size_t SH_L1   = (size_t)(68 * 72 + 68 * 136) * 2;      // 28,288
    const size_t SH_L2   = (size_t)(66 * 136) * 4;                // 35,904
    const size_t SH_F    = SH_L2;

    if (ov) {
        // zero L2 initial state (h2a, c2); L1 step 0 handles its own zeros
        // via the HZ body (writes c1/h1b fully, so no memset needed for L1).
        hipMemsetAsync(h2a, 0, HB, stream);
        hipMemsetAsync(c2, 0, CB, stream);

        // L1 step 0 (h==0): x-conv only, writes h1b + ws seq buf A
        convlstm_step<32, 5, true, true><<<dim3(512), dim3(NT), SH_L1HZ, stream>>>(
            x1p, x1B, h1a, c1, Wp1, Up1, b1, h1b, sqA, sqB,
            nullptr, 0);

        short* hc1 = h1b; short* hn1 = h1a;
        short* hc2 = h2a; short* hn2 = h2b;
        for (int t = 1; t < 10; ++t) {
            short* seq_w = (t & 1) ? sqB_ : sqA;       // L1 writes seq[t]
            short* seq_r = (t & 1) ? sqA : sqB_;       // L2 reads seq[t-1]
            convlstm_fused<<<dim3(1024), dim3(NT), SH_F, stream>>>(
                x1p + (size_t)t * x1T, x1B, hc1, c1, Wp1, Up1, b1, hn1,
                seq_w, sqB,
                seq_r, sqB, hc2, c2, Wp2, Up2, b2, hn2,
                out + (size_t)(t - 1) * oT, oB);
            short* tmp;
            tmp = hc1; hc1 = hn1; hn1 = tmp;
            tmp = hc2; hc2 = hn2; hn2 = tmp;
        }
        // L2 step 9 (standalone): reads seq[9] (buf B), writes out[9]
        // directly; h-state no longer needed -> h_next = nullptr.
        convlstm_step<64, 3, false, false><<<dim3(512), dim3(NT), SH_L2, stream>>>(
            sqB_, sqB, hc2, c2, Wp2, Up2, b2, nullptr,
            nullptr, 0, out + (size_t)9 * oT, oB);
    } else {
        // ---- serial fallback (R5-verified footprint; seq in d_out slots,
        //      relu_copy one step delayed as before) ----
        short* seqs = (short*)d_out;
        convlstm_step<32, 5, true, true><<<dim3(512), dim3(NT), SH_L1HZ, stream>>>(
            x1p, x1B, h1a, c1, Wp1, Up1, b1, h1b, seqs, oB * 2,
            nullptr, 0);
        short* hc = h1b; short* hn = h1a;
        for (int t = 1; t < 10; ++t) {
            convlstm_step<32, 5, true, false><<<dim3(512), dim3(NT), SH_L1, stream>>>(
                x1p + (size_t)t * x1T, x1B, hc, c1, Wp1, Up1, b1, hn,
                seqs + (size_t)t * oT * 2, oB * 2, nullptr, 0);
            short* tmp = hc; hc = hn; hn = tmp;
        }
        // L2 step 0: zero h (clobber hc, free now) + zero c, generic body.
        hipMemsetAsync(hc, 0, HB, stream);
        hipMemsetAsync(c2, 0, CB, stream);
        convlstm_step<64, 3, false, false><<<dim3(512), dim3(NT), SH_L2, stream>>>(
            seqs, oB * 2, hc, c2, Wp2, Up2, b2, hn, nullptr, 0,
            nullptr, 0);
        relu_copy<<<dim3(8192), dim3(NTU), 0, stream>>>(hn, out, oB);
        { short* tmp = hc; hc = hn; hn = tmp; }
        for (int t = 1; t < 10; ++t) {
            convlstm_step<64, 3, false, false><<<dim3(512), dim3(NT), SH_L2, stream>>>(
                seqs + (size_t)t * oT * 2, oB * 2, hc, c2, Wp2, Up2, b2, hn,
                nullptr, 0, nullptr, 0);
            relu_copy<<<dim3(8192), dim3(NTU), 0, stream>>>(hn, out + (size_t)t * oT, oB);
            short* tmp = hc; hc = hn; hn = tmp;
        }
    }
}